// Round 3
// baseline (624.100 us; speedup 1.0000x reference)
//
#include <hip/hip_runtime.h>

// Self-attention B=4, S=4096, D=1024, fp32 in/out.
// Round 3: 32x32x16 bf16 MFMA (higher matrix-pipe rate), launch_bounds(256,4)
// for 4 blocks/CU, fused single cvt dispatch. Keeps round-2 global_load_lds
// width=16 staging with XOR chunk swizzle.

typedef unsigned short u16;
typedef __attribute__((ext_vector_type(8))) short bf16x8;
typedef __attribute__((ext_vector_type(16))) float f32x16;

__device__ __forceinline__ float bf2f(u16 h) {
    unsigned int x = ((unsigned int)h) << 16;
    float f;
    __builtin_memcpy(&f, &x, 4);
    return f;
}

__device__ __forceinline__ u16 f2bf(float f) {
    unsigned int x;
    __builtin_memcpy(&x, &f, 4);
    unsigned int r = (x + 0x7FFFu + ((x >> 16) & 1u)) >> 16;  // RNE
    return (u16)r;
}

__device__ __forceinline__ void load16_lds(const u16* g, u16* l) {
    __builtin_amdgcn_global_load_lds(
        (const __attribute__((address_space(1))) void*)g,
        (__attribute__((address_space(3))) void*)l, 16, 0, 0);
}

// ------------- fused fp32 -> bf16 convert: x, Wq, Wk, Wv in one dispatch ----
// x: 4194304 float4s, each W: 262144 (=2^18) float4s. Grid sized exactly.
__global__ __launch_bounds__(256) void cvt_all(
    const float* __restrict__ x, const float* __restrict__ wq,
    const float* __restrict__ wk, const float* __restrict__ wv,
    u16* __restrict__ xo, u16* __restrict__ qo, u16* __restrict__ ko,
    u16* __restrict__ vo) {
    int i = blockIdx.x * 256 + threadIdx.x;
    const float* src;
    u16* dst;
    int idx;
    if (i < 4194304) {
        src = x; dst = xo; idx = i;
    } else {
        int j = i - 4194304;
        int sel = j >> 18;
        idx = j & 262143;
        src = (sel == 0) ? wq : (sel == 1) ? wk : wv;
        dst = (sel == 0) ? qo : (sel == 1) ? ko : vo;
    }
    float4 f = ((const float4*)src)[idx];
    ushort4 o;
    o.x = f2bf(f.x); o.y = f2bf(f.y); o.z = f2bf(f.z); o.w = f2bf(f.w);
    ((ushort4*)dst)[idx] = o;
}

// ---------------- shared MFMA core: 128x128 tile, BK=64, 4 waves 2x2 -------
// 32x32x16 bf16 MFMA, 2x2 tiles per wave (64x64).
// LDS: unpadded 64-elem rows, chunk c of row r stored at position c^(r&7).
// A/B frag: row(col)=lane&31, k = (lane>>5)*8 + j.
// C/D frag: col=lane&31, row = (reg&3) + 8*(reg>>2) + 4*(lane>>5).
__device__ __forceinline__ void mfma_core(
    const u16* __restrict__ A, const u16* __restrict__ B, int K, int ldA,
    int ldB, size_t rowA0, size_t rowB0, u16* As, u16* Bs, f32x16 acc[2][2]) {
    const int t = threadIdx.x;
    const int lane = t & 63;
    const int wave = t >> 6;
    const int wm = (wave >> 1) * 64;
    const int wn = (wave & 1) * 64;
    const int l31 = lane & 31;
    const int kh = lane >> 5;
    const int rl = lane >> 3;                 // staging row within 8-row call
    const int swz = ((lane & 7) ^ rl) << 3;   // swizzled source chunk (elems)

#pragma unroll
    for (int i = 0; i < 2; ++i)
#pragma unroll
        for (int j = 0; j < 2; ++j)
#pragma unroll
            for (int r = 0; r < 16; ++r) acc[i][j][r] = 0.f;

    const u16* ga = A + (rowA0 + (size_t)(wave * 32 + rl)) * (size_t)ldA + swz;
    const u16* gb = B + (rowB0 + (size_t)(wave * 32 + rl)) * (size_t)ldB + swz;
    u16* la = As + wave * 2048;
    u16* lb = Bs + wave * 2048;

    const int xr = l31 & 7;

    for (int kb = 0; kb < K; kb += 64) {
#pragma unroll
        for (int p = 0; p < 4; ++p) {
            load16_lds(ga + (size_t)(p * 8) * ldA + kb, la + p * 512);
            load16_lds(gb + (size_t)(p * 8) * ldB + kb, lb + p * 512);
        }
        __syncthreads();
#pragma unroll
        for (int ks = 0; ks < 4; ++ks) {        // k-step of 16
            const int phys = ((ks * 2 + kh) ^ xr) << 3;
            bf16x8 a[2], b[2];
#pragma unroll
            for (int i = 0; i < 2; ++i) {
                a[i] = *(const bf16x8*)(As + (wm + i * 32 + l31) * 64 + phys);
                b[i] = *(const bf16x8*)(Bs + (wn + i * 32 + l31) * 64 + phys);
            }
#pragma unroll
            for (int i = 0; i < 2; ++i)
#pragma unroll
                for (int j = 0; j < 2; ++j)
                    acc[i][j] = __builtin_amdgcn_mfma_f32_32x32x16_bf16(
                        a[i], b[j], acc[i][j], 0, 0, 0);
        }
        __syncthreads();
    }
}

// ---------------- fused QKV projection ----------------
// z=0: Qb natural, z=1: Kb natural, z=2: Vt transposed [b][d][s]; all + bias.
__global__ __launch_bounds__(256, 4) void proj_qkv(
    const u16* __restrict__ x, const u16* __restrict__ w0,
    const u16* __restrict__ w1, const u16* __restrict__ w2,
    const float* __restrict__ b0, const float* __restrict__ b1,
    const float* __restrict__ b2, u16* __restrict__ Qb, u16* __restrict__ Kb,
    u16* __restrict__ Vt) {
    __shared__ __align__(16) u16 As[128 * 64];
    __shared__ __align__(16) u16 Bs[128 * 64];
    const int z = blockIdx.z;
    const u16* W = (z == 0) ? w0 : (z == 1) ? w1 : w2;
    const float* bias = (z == 0) ? b0 : (z == 1) ? b1 : b2;

    const size_t rowA0 = (size_t)blockIdx.y * 128;
    const size_t rowB0 = (size_t)blockIdx.x * 128;
    f32x16 acc[2][2];
    mfma_core(x, W, 1024, 1024, 1024, rowA0, rowB0, As, Bs, acc);

    const int lane = threadIdx.x & 63;
    const int wave = threadIdx.x >> 6;
    const int wm = (wave >> 1) * 64;
    const int wn = (wave & 1) * 64;
    const int l31 = lane & 31;
    const int kh = lane >> 5;

#pragma unroll
    for (int i = 0; i < 2; ++i) {
#pragma unroll
        for (int j = 0; j < 2; ++j) {
            const int col = (int)rowB0 + wn + j * 32 + l31;
            const float bv = bias[col];
#pragma unroll
            for (int g = 0; g < 4; ++g) {
                const int r0 = (int)rowA0 + wm + i * 32 + g * 8 + kh * 4;
                if (z < 2) {
                    u16* C = z ? Kb : Qb;
#pragma unroll
                    for (int r = 0; r < 4; ++r)
                        C[(size_t)(r0 + r) * 1024 + col] =
                            f2bf(acc[i][j][g * 4 + r] + bv);
                } else {
                    const int batch = r0 >> 12;
                    const int s0 = r0 & 4095;
                    ushort4 o;
                    o.x = f2bf(acc[i][j][g * 4 + 0] + bv);
                    o.y = f2bf(acc[i][j][g * 4 + 1] + bv);
                    o.z = f2bf(acc[i][j][g * 4 + 2] + bv);
                    o.w = f2bf(acc[i][j][g * 4 + 3] + bv);
                    *(ushort4*)(Vt + (size_t)batch * 4194304 +
                                (size_t)col * 4096 + s0) = o;
                }
            }
        }
    }
}

// ---------------- generic NT GEMM, z-strided ----------------
// MODE 2: out bf16 * scale (scores);  MODE 3: out fp32 (PV).
template <int MODE>
__global__ __launch_bounds__(256, 4) void gemm_nt(
    const u16* __restrict__ A0, const u16* __restrict__ B0,
    void* __restrict__ Cv, int K, int ldA, int ldB, int ldC, float scale,
    size_t sAz, size_t sBz, size_t sCz) {
    __shared__ __align__(16) u16 As[128 * 64];
    __shared__ __align__(16) u16 Bs[128 * 64];
    const size_t z = blockIdx.z;
    const u16* A = A0 + z * sAz;
    const u16* B = B0 + z * sBz;

    const size_t rowA0 = (size_t)blockIdx.y * 128;
    const size_t rowB0 = (size_t)blockIdx.x * 128;
    f32x16 acc[2][2];
    mfma_core(A, B, K, ldA, ldB, rowA0, rowB0, As, Bs, acc);

    const int lane = threadIdx.x & 63;
    const int wave = threadIdx.x >> 6;
    const int wm = (wave >> 1) * 64;
    const int wn = (wave & 1) * 64;
    const int l31 = lane & 31;
    const int kh = lane >> 5;

#pragma unroll
    for (int i = 0; i < 2; ++i) {
#pragma unroll
        for (int j = 0; j < 2; ++j) {
            const int col = (int)rowB0 + wn + j * 32 + l31;
#pragma unroll
            for (int g = 0; g < 4; ++g) {
                const int r0 = (int)rowA0 + wm + i * 32 + g * 8 + kh * 4;
                if (MODE == 2) {
                    u16* C = (u16*)Cv + z * sCz;
#pragma unroll
                    for (int r = 0; r < 4; ++r)
                        C[(size_t)(r0 + r) * ldC + col] =
                            f2bf(acc[i][j][g * 4 + r] * scale);
                } else {
                    float* C = (float*)Cv + z * sCz;
#pragma unroll
                    for (int r = 0; r < 4; ++r)
                        C[(size_t)(r0 + r) * ldC + col] = acc[i][j][g * 4 + r];
                }
            }
        }
    }
}

// ---------------- in-place row softmax over 4096 bf16 ----------------
__global__ __launch_bounds__(256) void softmax_inplace(u16* __restrict__ P) {
    u16* p = P + (size_t)blockIdx.x * 4096;
    const int t = threadIdx.x;
    const int lane = t & 63;
    const int wave = t >> 6;
    __shared__ float redmax[4];
    __shared__ float redsum[4];

    uint4 raw0 = *(const uint4*)(p + t * 8);
    uint4 raw1 = *(const uint4*)(p + 2048 + t * 8);
    float v[16];
    {
        const u16* h0 = (const u16*)&raw0;
        const u16* h1 = (const u16*)&raw1;
#pragma unroll
        for (int i = 0; i < 8; ++i) v[i] = bf2f(h0[i]);
#pragma unroll
        for (int i = 0; i < 8; ++i) v[8 + i] = bf2f(h1[i]);
    }
    float m = v[0];
#pragma unroll
    for (int i = 1; i < 16; ++i) m = fmaxf(m, v[i]);
#pragma unroll
    for (int o = 32; o >= 1; o >>= 1) m = fmaxf(m, __shfl_xor(m, o));
    if (lane == 0) redmax[wave] = m;
    __syncthreads();
    m = fmaxf(fmaxf(redmax[0], redmax[1]), fmaxf(redmax[2], redmax[3]));

    float s = 0.f;
#pragma unroll
    for (int i = 0; i < 16; ++i) {
        v[i] = __expf(v[i] - m);
        s += v[i];
    }
#pragma unroll
    for (int o = 32; o >= 1; o >>= 1) s += __shfl_xor(s, o);
    if (lane == 0) redsum[wave] = s;
    __syncthreads();
    s = redsum[0] + redsum[1] + redsum[2] + redsum[3];
    const float inv = 1.0f / s;

    u16 ho[16];
#pragma unroll
    for (int i = 0; i < 16; ++i) ho[i] = f2bf(v[i] * inv);
    *(uint4*)(p + t * 8) = *(const uint4*)&ho[0];
    *(uint4*)(p + 2048 + t * 8) = *(const uint4*)&ho[8];
}

// ---------------- host launcher ----------------
extern "C" void kernel_launch(void* const* d_in, const int* in_sizes, int n_in,
                              void* d_out, int out_size, void* d_ws, size_t ws_size,
                              hipStream_t stream) {
    const float* x  = (const float*)d_in[0];
    const float* Wq = (const float*)d_in[1];
    const float* bq = (const float*)d_in[2];
    const float* Wk = (const float*)d_in[3];
    const float* bk = (const float*)d_in[4];
    const float* Wv = (const float*)d_in[5];
    const float* bv = (const float*)d_in[6];
    float* out = (float*)d_out;

    const bool big = ws_size >= (size_t)224 * 1024 * 1024;
    char* w = (char*)d_ws;
    u16 *x_bf, *wq_bf, *wk_bf, *wv_bf, *Qb, *Kb, *Vt, *SP;
    if (big) {
        // SP[4] occupies [0,128MiB); x_bf + W bufs alias its head (dead
        // before SP is written — stream order guarantees proj finished).
        SP    = (u16*)(w);
        x_bf  = (u16*)(w);
        wq_bf = (u16*)(w + 33554432);
        wk_bf = (u16*)(w + 35651584);
        wv_bf = (u16*)(w + 37748736);
        Qb    = (u16*)(w + 134217728);
        Kb    = (u16*)(w + 167772160);
        Vt    = (u16*)(w + 201326592);
    } else {
        x_bf  = (u16*)(w);
        wq_bf = (u16*)(w + 33554432);
        wk_bf = (u16*)(w + 35651584);
        wv_bf = (u16*)(w + 37748736);
        Qb    = (u16*)(w + 39845888);
        Kb    = (u16*)(w + 73400320);
        Vt    = (u16*)(w + 106954752);
        SP    = (u16*)(w + 140509184);  // single 32 MiB buffer
    }

    // 1) convert all inputs to bf16 in one dispatch (exact-sized grid)
    cvt_all<<<19456, 256, 0, stream>>>(x, Wq, Wk, Wv, x_bf, wq_bf, wk_bf, wv_bf);

    // 2) fused projections: M=16384, N=1024, K=1024, z = {Q,K,V}
    proj_qkv<<<dim3(8, 128, 3), 256, 0, stream>>>(
        x_bf, wq_bf, wk_bf, wv_bf, bq, bk, bv, Qb, Kb, Vt);

    if (big) {
        // 3) batched scores: [b] Q Kt /32 -> bf16
        gemm_nt<2><<<dim3(32, 32, 4), 256, 0, stream>>>(
            Qb, Kb, SP, 1024, 1024, 1024, 4096, 0.03125f,
            4194304, 4194304, 16777216);
        // 4) batched softmax over all 16384 rows
        softmax_inplace<<<16384, 256, 0, stream>>>(SP);
        // 5) batched PV: O = P Vt -> fp32
        gemm_nt<3><<<dim3(8, 32, 4), 256, 0, stream>>>(
            SP, Vt, out, 4096, 4096, 4096, 1024, 1.f,
            16777216, 4194304, 4194304);
    } else {
        for (int b = 0; b < 4; ++b) {
            const size_t off = (size_t)b * 4194304;
            gemm_nt<2><<<dim3(32, 32, 1), 256, 0, stream>>>(
                Qb + off, Kb + off, SP, 1024, 1024, 1024, 4096, 0.03125f,
                0, 0, 0);
            softmax_inplace<<<4096, 256, 0, stream>>>(SP);
            gemm_nt<3><<<dim3(8, 32, 1), 256, 0, stream>>>(
                SP, Vt + off, out + off, 4096, 4096, 4096, 1024, 1.f,
                0, 0, 0);
        }
    }
}

// Round 4
// 579.436 us; speedup vs baseline: 1.0771x; 1.0771x over previous
//
#include <hip/hip_runtime.h>

// Self-attention B=4, S=4096, D=1024, fp32 in/out.
// Round 4: revert to 16x16x32 core (round-2, 0 bank conflicts). Fuse softmax
// away: scores epilogue writes P' = exp(s/32) and atomically accumulates
// per-row sums L; PV epilogue divides by L. No standalone softmax dispatch.

typedef unsigned short u16;
typedef __attribute__((ext_vector_type(8))) short bf16x8;
typedef __attribute__((ext_vector_type(4))) float f32x4;

__device__ __forceinline__ float bf2f(u16 h) {
    unsigned int x = ((unsigned int)h) << 16;
    float f;
    __builtin_memcpy(&f, &x, 4);
    return f;
}

__device__ __forceinline__ u16 f2bf(float f) {
    unsigned int x;
    __builtin_memcpy(&x, &f, 4);
    unsigned int r = (x + 0x7FFFu + ((x >> 16) & 1u)) >> 16;  // RNE
    return (u16)r;
}

__device__ __forceinline__ void load16_lds(const u16* g, u16* l) {
    __builtin_amdgcn_global_load_lds(
        (const __attribute__((address_space(1))) void*)g,
        (__attribute__((address_space(3))) void*)l, 16, 0, 0);
}

// ------------- fused fp32 -> bf16 convert: x, Wq, Wk, Wv in one dispatch ----
__global__ __launch_bounds__(256) void cvt_all(
    const float* __restrict__ x, const float* __restrict__ wq,
    const float* __restrict__ wk, const float* __restrict__ wv,
    u16* __restrict__ xo, u16* __restrict__ qo, u16* __restrict__ ko,
    u16* __restrict__ vo) {
    int i = blockIdx.x * 256 + threadIdx.x;
    const float* src;
    u16* dst;
    int idx;
    if (i < 4194304) {
        src = x; dst = xo; idx = i;
    } else {
        int j = i - 4194304;
        int sel = j >> 18;
        idx = j & 262143;
        src = (sel == 0) ? wq : (sel == 1) ? wk : wv;
        dst = (sel == 0) ? qo : (sel == 1) ? ko : vo;
    }
    float4 f = ((const float4*)src)[idx];
    ushort4 o;
    o.x = f2bf(f.x); o.y = f2bf(f.y); o.z = f2bf(f.z); o.w = f2bf(f.w);
    ((ushort4*)dst)[idx] = o;
}

// ---------------- shared MFMA core (round-2): 128x128, BK=64, 4 waves 2x2 --
// 16x16x32 bf16 MFMA, 4x4 tiles per wave. LDS unpadded 64-elem rows, chunk c
// of row r at position c^(r&7) (conflict-free, measured 0).
// C/D: col = lane&15, row = (lane>>4)*4 + reg.
__device__ __forceinline__ void mfma_core(
    const u16* __restrict__ A, const u16* __restrict__ B, int K, int ldA,
    int ldB, size_t rowA0, size_t rowB0, u16* As, u16* Bs, f32x4 acc[4][4]) {
    const int t = threadIdx.x;
    const int lane = t & 63;
    const int wave = t >> 6;
    const int wm = (wave >> 1) * 64;
    const int wn = (wave & 1) * 64;
    const int lm = lane & 15;
    const int qd = lane >> 4;
    const int kx = lm & 7;
    const int rl = lane >> 3;                 // staging row within 8-row call
    const int swz = ((lane & 7) ^ rl) << 3;   // swizzled source chunk (elems)

#pragma unroll
    for (int i = 0; i < 4; ++i)
#pragma unroll
        for (int j = 0; j < 4; ++j) acc[i][j] = (f32x4){0.f, 0.f, 0.f, 0.f};

    const u16* ga = A + (rowA0 + (size_t)(wave * 32 + rl)) * (size_t)ldA + swz;
    const u16* gb = B + (rowB0 + (size_t)(wave * 32 + rl)) * (size_t)ldB + swz;
    u16* la = As + wave * 2048;
    u16* lb = Bs + wave * 2048;

    for (int kb = 0; kb < K; kb += 64) {
#pragma unroll
        for (int p = 0; p < 4; ++p) {
            load16_lds(ga + (size_t)(p * 8) * ldA + kb, la + p * 512);
            load16_lds(gb + (size_t)(p * 8) * ldB + kb, lb + p * 512);
        }
        __syncthreads();
#pragma unroll
        for (int k0 = 0; k0 < 64; k0 += 32) {
            const int q0 = k0 >> 3;  // chunk base: 0 or 4
            const int cofs = (((q0 + qd) ^ kx) << 3);
            bf16x8 a[4], b[4];
#pragma unroll
            for (int i = 0; i < 4; ++i) {
                a[i] = *(const bf16x8*)(As + (wm + i * 16 + lm) * 64 + cofs);
                b[i] = *(const bf16x8*)(Bs + (wn + i * 16 + lm) * 64 + cofs);
            }
#pragma unroll
            for (int i = 0; i < 4; ++i)
#pragma unroll
                for (int j = 0; j < 4; ++j)
                    acc[i][j] = __builtin_amdgcn_mfma_f32_16x16x32_bf16(
                        a[i], b[j], acc[i][j], 0, 0, 0);
        }
        __syncthreads();
    }
}

// ---------------- fused QKV projection ----------------
__global__ __launch_bounds__(256, 3) void proj_qkv(
    const u16* __restrict__ x, const u16* __restrict__ w0,
    const u16* __restrict__ w1, const u16* __restrict__ w2,
    const float* __restrict__ b0, const float* __restrict__ b1,
    const float* __restrict__ b2, u16* __restrict__ Qb, u16* __restrict__ Kb,
    u16* __restrict__ Vt) {
    __shared__ __align__(16) u16 As[128 * 64];
    __shared__ __align__(16) u16 Bs[128 * 64];
    const int z = blockIdx.z;
    const u16* W = (z == 0) ? w0 : (z == 1) ? w1 : w2;
    const float* bias = (z == 0) ? b0 : (z == 1) ? b1 : b2;

    const size_t rowA0 = (size_t)blockIdx.y * 128;
    const size_t rowB0 = (size_t)blockIdx.x * 128;
    f32x4 acc[4][4];
    mfma_core(x, W, 1024, 1024, 1024, rowA0, rowB0, As, Bs, acc);

    const int lane = threadIdx.x & 63;
    const int wave = threadIdx.x >> 6;
    const int wm = (wave >> 1) * 64;
    const int wn = (wave & 1) * 64;
    const int lm = lane & 15;
    const int qd = lane >> 4;

#pragma unroll
    for (int i = 0; i < 4; ++i) {
        const int r0 = (int)rowA0 + wm + i * 16 + qd * 4;
#pragma unroll
        for (int j = 0; j < 4; ++j) {
            const int col = (int)rowB0 + wn + j * 16 + lm;
            const float bv = bias[col];
            if (z < 2) {
                u16* C = z ? Kb : Qb;
#pragma unroll
                for (int r = 0; r < 4; ++r)
                    C[(size_t)(r0 + r) * 1024 + col] = f2bf(acc[i][j][r] + bv);
            } else {
                const int batch = r0 >> 12;
                const int s0 = r0 & 4095;
                ushort4 o;
                o.x = f2bf(acc[i][j][0] + bv);
                o.y = f2bf(acc[i][j][1] + bv);
                o.z = f2bf(acc[i][j][2] + bv);
                o.w = f2bf(acc[i][j][3] + bv);
                *(ushort4*)(Vt + (size_t)batch * 4194304 +
                            (size_t)col * 4096 + s0) = o;
            }
        }
    }
}

// ------------- scores: P' = exp(QKt/32) bf16, L[row] += row-sums ------------
__global__ __launch_bounds__(256, 3) void gemm_scores(
    const u16* __restrict__ Qb, const u16* __restrict__ Kb,
    u16* __restrict__ SP, float* __restrict__ L) {
    __shared__ __align__(16) u16 As[128 * 64];
    __shared__ __align__(16) u16 Bs[128 * 64];
    __shared__ float Ls[256];  // [row_local][wave&1]
    const size_t z = blockIdx.z;
    const u16* A = Qb + z * 4194304;
    const u16* B = Kb + z * 4194304;
    u16* C = SP + z * 16777216;

    const size_t rowA0 = (size_t)blockIdx.y * 128;
    const size_t rowB0 = (size_t)blockIdx.x * 128;
    f32x4 acc[4][4];
    mfma_core(A, B, 1024, 1024, 1024, rowA0, rowB0, As, Bs, acc);

    const int lane = threadIdx.x & 63;
    const int wave = threadIdx.x >> 6;
    const int wm = (wave >> 1) * 64;
    const int wn = (wave & 1) * 64;
    const int lm = lane & 15;
    const int qd = lane >> 4;

#pragma unroll
    for (int i = 0; i < 4; ++i) {
        const int rl0 = wm + i * 16 + qd * 4;     // local row base
        float part[4] = {0.f, 0.f, 0.f, 0.f};
#pragma unroll
        for (int j = 0; j < 4; ++j) {
            const int col = (int)rowB0 + wn + j * 16 + lm;
            u16 o[4];
#pragma unroll
            for (int r = 0; r < 4; ++r) {
                float e = __expf(acc[i][j][r] * 0.03125f);
                o[r] = f2bf(e);
                part[r] += e;
            }
#pragma unroll
            for (int r = 0; r < 4; ++r)
                C[(size_t)(rowA0 + rl0 + r) * 4096 + col] = o[r];
        }
        // reduce each row-partial across the 16 lanes of this quad
#pragma unroll
        for (int r = 0; r < 4; ++r) {
#pragma unroll
            for (int o = 8; o >= 1; o >>= 1) part[r] += __shfl_xor(part[r], o);
        }
        if (lm == 0) {
#pragma unroll
            for (int r = 0; r < 4; ++r)
                Ls[(rl0 + r) * 2 + (wave & 1)] = part[r];
        }
    }
    __syncthreads();
    const int t = threadIdx.x;
    if (t < 128)
        atomicAdd(L + z * 4096 + rowA0 + t, Ls[t * 2] + Ls[t * 2 + 1]);
}

// ------------- PV: O = (P' Vt) / L -> fp32 ------------
__global__ __launch_bounds__(256, 3) void gemm_pv(
    const u16* __restrict__ SP, const u16* __restrict__ Vt,
    float* __restrict__ out, const float* __restrict__ L) {
    __shared__ __align__(16) u16 As[128 * 64];
    __shared__ __align__(16) u16 Bs[128 * 64];
    const size_t z = blockIdx.z;
    const u16* A = SP + z * 16777216;
    const u16* B = Vt + z * 4194304;
    float* C = out + z * 4194304;

    const size_t rowA0 = (size_t)blockIdx.y * 128;
    const size_t rowB0 = (size_t)blockIdx.x * 128;
    f32x4 acc[4][4];
    mfma_core(A, B, 4096, 4096, 4096, rowA0, rowB0, As, Bs, acc);

    const int lane = threadIdx.x & 63;
    const int wave = threadIdx.x >> 6;
    const int wm = (wave >> 1) * 64;
    const int wn = (wave & 1) * 64;
    const int lm = lane & 15;
    const int qd = lane >> 4;

#pragma unroll
    for (int i = 0; i < 4; ++i) {
        const int r0 = (int)rowA0 + wm + i * 16 + qd * 4;
        float inv[4];
#pragma unroll
        for (int r = 0; r < 4; ++r) inv[r] = 1.0f / L[z * 4096 + r0 + r];
#pragma unroll
        for (int j = 0; j < 4; ++j) {
            const int col = (int)rowB0 + wn + j * 16 + lm;
#pragma unroll
            for (int r = 0; r < 4; ++r)
                C[(size_t)(r0 + r) * 1024 + col] = acc[i][j][r] * inv[r];
        }
    }
}

// ---------------- fallback kernels (small-ws path, round-2 behavior) -------
template <int MODE>  // 2: bf16*scale, 3: fp32
__global__ __launch_bounds__(256, 3) void gemm_nt(
    const u16* __restrict__ A, const u16* __restrict__ B,
    void* __restrict__ Cv, int K, int ldA, int ldB, int ldC, float scale) {
    __shared__ __align__(16) u16 As[128 * 64];
    __shared__ __align__(16) u16 Bs[128 * 64];
    const size_t rowA0 = (size_t)blockIdx.y * 128;
    const size_t rowB0 = (size_t)blockIdx.x * 128;
    f32x4 acc[4][4];
    mfma_core(A, B, K, ldA, ldB, rowA0, rowB0, As, Bs, acc);

    const int lane = threadIdx.x & 63;
    const int wave = threadIdx.x >> 6;
    const int wm = (wave >> 1) * 64;
    const int wn = (wave & 1) * 64;
    const int lm = lane & 15;
    const int qd = lane >> 4;

#pragma unroll
    for (int i = 0; i < 4; ++i) {
        const int r0 = (int)rowA0 + wm + i * 16 + qd * 4;
#pragma unroll
        for (int j = 0; j < 4; ++j) {
            const int col = (int)rowB0 + wn + j * 16 + lm;
            if (MODE == 2) {
                u16* C = (u16*)Cv;
#pragma unroll
                for (int r = 0; r < 4; ++r)
                    C[(size_t)(r0 + r) * ldC + col] = f2bf(acc[i][j][r] * scale);
            } else {
                float* C = (float*)Cv;
#pragma unroll
                for (int r = 0; r < 4; ++r)
                    C[(size_t)(r0 + r) * ldC + col] = acc[i][j][r];
            }
        }
    }
}

__global__ __launch_bounds__(256) void softmax_inplace(u16* __restrict__ P) {
    u16* p = P + (size_t)blockIdx.x * 4096;
    const int t = threadIdx.x;
    const int lane = t & 63;
    const int wave = t >> 6;
    __shared__ float redmax[4];
    __shared__ float redsum[4];

    uint4 raw0 = *(const uint4*)(p + t * 8);
    uint4 raw1 = *(const uint4*)(p + 2048 + t * 8);
    float v[16];
    {
        const u16* h0 = (const u16*)&raw0;
        const u16* h1 = (const u16*)&raw1;
#pragma unroll
        for (int i = 0; i < 8; ++i) v[i] = bf2f(h0[i]);
#pragma unroll
        for (int i = 0; i < 8; ++i) v[8 + i] = bf2f(h1[i]);
    }
    float m = v[0];
#pragma unroll
    for (int i = 1; i < 16; ++i) m = fmaxf(m, v[i]);
#pragma unroll
    for (int o = 32; o >= 1; o >>= 1) m = fmaxf(m, __shfl_xor(m, o));
    if (lane == 0) redmax[wave] = m;
    __syncthreads();
    m = fmaxf(fmaxf(redmax[0], redmax[1]), fmaxf(redmax[2], redmax[3]));

    float s = 0.f;
#pragma unroll
    for (int i = 0; i < 16; ++i) {
        v[i] = __expf(v[i] - m);
        s += v[i];
    }
#pragma unroll
    for (int o = 32; o >= 1; o >>= 1) s += __shfl_xor(s, o);
    if (lane == 0) redsum[wave] = s;
    __syncthreads();
    s = redsum[0] + redsum[1] + redsum[2] + redsum[3];
    const float inv = 1.0f / s;

    u16 ho[16];
#pragma unroll
    for (int i = 0; i < 16; ++i) ho[i] = f2bf(v[i] * inv);
    *(uint4*)(p + t * 8) = *(const uint4*)&ho[0];
    *(uint4*)(p + 2048 + t * 8) = *(const uint4*)&ho[8];
}

// ---------------- host launcher ----------------
extern "C" void kernel_launch(void* const* d_in, const int* in_sizes, int n_in,
                              void* d_out, int out_size, void* d_ws, size_t ws_size,
                              hipStream_t stream) {
    const float* x  = (const float*)d_in[0];
    const float* Wq = (const float*)d_in[1];
    const float* bq = (const float*)d_in[2];
    const float* Wk = (const float*)d_in[3];
    const float* bk = (const float*)d_in[4];
    const float* Wv = (const float*)d_in[5];
    const float* bv = (const float*)d_in[6];
    float* out = (float*)d_out;

    const bool big = ws_size >= (size_t)234946560;  // 224 MiB + 64 KiB for L
    char* w = (char*)d_ws;
    u16 *x_bf, *wq_bf, *wk_bf, *wv_bf, *Qb, *Kb, *Vt, *SP;
    float* L = nullptr;
    if (big) {
        // SP[4] at [0,128MiB); x_bf/W alias its head (dead before SP write).
        SP    = (u16*)(w);
        x_bf  = (u16*)(w);
        wq_bf = (u16*)(w + 33554432);
        wk_bf = (u16*)(w + 35651584);
        wv_bf = (u16*)(w + 37748736);
        Qb    = (u16*)(w + 134217728);
        Kb    = (u16*)(w + 167772160);
        Vt    = (u16*)(w + 201326592);
        L     = (float*)(w + 234881024);
    } else {
        x_bf  = (u16*)(w);
        wq_bf = (u16*)(w + 33554432);
        wk_bf = (u16*)(w + 35651584);
        wv_bf = (u16*)(w + 37748736);
        Qb    = (u16*)(w + 39845888);
        Kb    = (u16*)(w + 73400320);
        Vt    = (u16*)(w + 106954752);
        SP    = (u16*)(w + 140509184);
    }

    // 1) convert all inputs to bf16 in one dispatch (exact-sized grid)
    cvt_all<<<19456, 256, 0, stream>>>(x, Wq, Wk, Wv, x_bf, wq_bf, wk_bf, wv_bf);

    // 2) fused projections: M=16384, N=1024, K=1024, z = {Q,K,V}
    proj_qkv<<<dim3(8, 128, 3), 256, 0, stream>>>(
        x_bf, wq_bf, wk_bf, wv_bf, bq, bk, bv, Qb, Kb, Vt);

    if (big) {
        hipMemsetAsync(L, 0, 16384 * sizeof(float), stream);
        // 3) P' = exp(QKt/32), L = row sums
        gemm_scores<<<dim3(32, 32, 4), 256, 0, stream>>>(Qb, Kb, SP, L);
        // 4) O = (P' Vt) / L
        gemm_pv<<<dim3(8, 32, 4), 256, 0, stream>>>(SP, Vt, out, L);
    } else {
        for (int b = 0; b < 4; ++b) {
            const size_t off = (size_t)b * 4194304;
            gemm_nt<2><<<dim3(32, 32, 1), 256, 0, stream>>>(
                Qb + off, Kb + off, SP, 1024, 1024, 1024, 4096, 0.03125f);
            softmax_inplace<<<4096, 256, 0, stream>>>(SP);
            gemm_nt<3><<<dim3(8, 32, 1), 256, 0, stream>>>(
                SP, Vt + off, out + off, 4096, 4096, 4096, 1024, 1.f);
        }
    }
}

// Round 5
// 528.237 us; speedup vs baseline: 1.1815x; 1.0969x over previous
//
#include <hip/hip_runtime.h>

// Self-attention B=4, S=4096, D=1024, fp32 in/out.
// Round 5: restore occupancy lost in R4 — __launch_bounds__(256,4) caps
// epilogue VGPR; PV reads 1/L through LDS (no long-lived inv regs); XCD
// swizzle (row-block = blockIdx.x) for A-tile L2 reuse in scores/PV; L
// zeroing folded into cvt_all (memset dispatch removed).

typedef unsigned short u16;
typedef __attribute__((ext_vector_type(8))) short bf16x8;
typedef __attribute__((ext_vector_type(4))) float f32x4;

__device__ __forceinline__ float bf2f(u16 h) {
    unsigned int x = ((unsigned int)h) << 16;
    float f;
    __builtin_memcpy(&f, &x, 4);
    return f;
}

__device__ __forceinline__ u16 f2bf(float f) {
    unsigned int x;
    __builtin_memcpy(&x, &f, 4);
    unsigned int r = (x + 0x7FFFu + ((x >> 16) & 1u)) >> 16;  // RNE
    return (u16)r;
}

__device__ __forceinline__ void load16_lds(const u16* g, u16* l) {
    __builtin_amdgcn_global_load_lds(
        (const __attribute__((address_space(1))) void*)g,
        (__attribute__((address_space(3))) void*)l, 16, 0, 0);
}

// ---- fused fp32 -> bf16 convert (x, Wq, Wk, Wv) + zero L, one dispatch ----
__global__ __launch_bounds__(256) void cvt_all(
    const float* __restrict__ x, const float* __restrict__ wq,
    const float* __restrict__ wk, const float* __restrict__ wv,
    u16* __restrict__ xo, u16* __restrict__ qo, u16* __restrict__ ko,
    u16* __restrict__ vo, float* __restrict__ L) {
    int i = blockIdx.x * 256 + threadIdx.x;
    if (i >= 4980736) {  // last 16 blocks: zero L (16384 floats)
        ((float4*)L)[i - 4980736] = (float4){0.f, 0.f, 0.f, 0.f};
        return;
    }
    const float* src;
    u16* dst;
    int idx;
    if (i < 4194304) {
        src = x; dst = xo; idx = i;
    } else {
        int j = i - 4194304;
        int sel = j >> 18;
        idx = j & 262143;
        src = (sel == 0) ? wq : (sel == 1) ? wk : wv;
        dst = (sel == 0) ? qo : (sel == 1) ? ko : vo;
    }
    float4 f = ((const float4*)src)[idx];
    ushort4 o;
    o.x = f2bf(f.x); o.y = f2bf(f.y); o.z = f2bf(f.z); o.w = f2bf(f.w);
    ((ushort4*)dst)[idx] = o;
}

// ---------------- shared MFMA core: 128x128, BK=64, 4 waves 2x2 ------------
// 16x16x32 bf16 MFMA, 4x4 tiles/wave. LDS unpadded 64-elem rows, chunk c of
// row r at position c^(r&7) (0 conflicts measured).
// C/D: col = lane&15, row = (lane>>4)*4 + reg.
__device__ __forceinline__ void mfma_core(
    const u16* __restrict__ A, const u16* __restrict__ B, int K, int ldA,
    int ldB, size_t rowA0, size_t rowB0, u16* As, u16* Bs, f32x4 acc[4][4]) {
    const int t = threadIdx.x;
    const int lane = t & 63;
    const int wave = t >> 6;
    const int wm = (wave >> 1) * 64;
    const int wn = (wave & 1) * 64;
    const int lm = lane & 15;
    const int qd = lane >> 4;
    const int kx = lm & 7;
    const int rl = lane >> 3;                 // staging row within 8-row call
    const int swz = ((lane & 7) ^ rl) << 3;   // swizzled source chunk (elems)

#pragma unroll
    for (int i = 0; i < 4; ++i)
#pragma unroll
        for (int j = 0; j < 4; ++j) acc[i][j] = (f32x4){0.f, 0.f, 0.f, 0.f};

    const u16* ga = A + (rowA0 + (size_t)(wave * 32 + rl)) * (size_t)ldA + swz;
    const u16* gb = B + (rowB0 + (size_t)(wave * 32 + rl)) * (size_t)ldB + swz;
    u16* la = As + wave * 2048;
    u16* lb = Bs + wave * 2048;

    for (int kb = 0; kb < K; kb += 64) {
#pragma unroll
        for (int p = 0; p < 4; ++p) {
            load16_lds(ga + (size_t)(p * 8) * ldA + kb, la + p * 512);
            load16_lds(gb + (size_t)(p * 8) * ldB + kb, lb + p * 512);
        }
        __syncthreads();
#pragma unroll
        for (int k0 = 0; k0 < 64; k0 += 32) {
            const int q0 = k0 >> 3;  // chunk base: 0 or 4
            const int cofs = (((q0 + qd) ^ kx) << 3);
            bf16x8 a[4], b[4];
#pragma unroll
            for (int i = 0; i < 4; ++i) {
                a[i] = *(const bf16x8*)(As + (wm + i * 16 + lm) * 64 + cofs);
                b[i] = *(const bf16x8*)(Bs + (wn + i * 16 + lm) * 64 + cofs);
            }
#pragma unroll
            for (int i = 0; i < 4; ++i)
#pragma unroll
                for (int j = 0; j < 4; ++j)
                    acc[i][j] = __builtin_amdgcn_mfma_f32_16x16x32_bf16(
                        a[i], b[j], acc[i][j], 0, 0, 0);
        }
        __syncthreads();
    }
}

// ---------------- fused QKV projection ----------------
__global__ __launch_bounds__(256, 4) void proj_qkv(
    const u16* __restrict__ x, const u16* __restrict__ w0,
    const u16* __restrict__ w1, const u16* __restrict__ w2,
    const float* __restrict__ b0, const float* __restrict__ b1,
    const float* __restrict__ b2, u16* __restrict__ Qb, u16* __restrict__ Kb,
    u16* __restrict__ Vt) {
    __shared__ __align__(16) u16 As[128 * 64];
    __shared__ __align__(16) u16 Bs[128 * 64];
    const int z = blockIdx.z;
    const u16* W = (z == 0) ? w0 : (z == 1) ? w1 : w2;
    const float* bias = (z == 0) ? b0 : (z == 1) ? b1 : b2;

    const size_t rowA0 = (size_t)blockIdx.y * 128;
    const size_t rowB0 = (size_t)blockIdx.x * 128;
    f32x4 acc[4][4];
    mfma_core(x, W, 1024, 1024, 1024, rowA0, rowB0, As, Bs, acc);

    const int lane = threadIdx.x & 63;
    const int wave = threadIdx.x >> 6;
    const int wm = (wave >> 1) * 64;
    const int wn = (wave & 1) * 64;
    const int lm = lane & 15;
    const int qd = lane >> 4;

#pragma unroll
    for (int i = 0; i < 4; ++i) {
        const int r0 = (int)rowA0 + wm + i * 16 + qd * 4;
#pragma unroll
        for (int j = 0; j < 4; ++j) {
            const int col = (int)rowB0 + wn + j * 16 + lm;
            const float bv = bias[col];
            if (z < 2) {
                u16* C = z ? Kb : Qb;
#pragma unroll
                for (int r = 0; r < 4; ++r)
                    C[(size_t)(r0 + r) * 1024 + col] = f2bf(acc[i][j][r] + bv);
            } else {
                const int batch = r0 >> 12;
                const int s0 = r0 & 4095;
                ushort4 o;
                o.x = f2bf(acc[i][j][0] + bv);
                o.y = f2bf(acc[i][j][1] + bv);
                o.z = f2bf(acc[i][j][2] + bv);
                o.w = f2bf(acc[i][j][3] + bv);
                *(ushort4*)(Vt + (size_t)batch * 4194304 +
                            (size_t)col * 4096 + s0) = o;
            }
        }
    }
}

// ------- scores: P' = exp(QKt/32) bf16, L[row] += row-sums ------------
// blockIdx.x = row-block (XCD swizzle: col-blocks of one row share id%8).
__global__ __launch_bounds__(256, 4) void gemm_scores(
    const u16* __restrict__ Qb, const u16* __restrict__ Kb,
    u16* __restrict__ SP, float* __restrict__ L) {
    __shared__ __align__(16) u16 As[128 * 64];
    __shared__ __align__(16) u16 Bs[128 * 64];
    __shared__ float Ls[256];  // [row_local][wave&1]
    const size_t z = blockIdx.z;
    const u16* A = Qb + z * 4194304;
    const u16* B = Kb + z * 4194304;
    u16* C = SP + z * 16777216;

    const size_t rowA0 = (size_t)blockIdx.x * 128;  // row-block (swizzled)
    const size_t rowB0 = (size_t)blockIdx.y * 128;
    f32x4 acc[4][4];
    mfma_core(A, B, 1024, 1024, 1024, rowA0, rowB0, As, Bs, acc);

    const int lane = threadIdx.x & 63;
    const int wave = threadIdx.x >> 6;
    const int wm = (wave >> 1) * 64;
    const int wn = (wave & 1) * 64;
    const int lm = lane & 15;
    const int qd = lane >> 4;

#pragma unroll
    for (int i = 0; i < 4; ++i) {
        const int rl0 = wm + i * 16 + qd * 4;     // local row base
        float part[4] = {0.f, 0.f, 0.f, 0.f};
#pragma unroll
        for (int j = 0; j < 4; ++j) {
            const int col = (int)rowB0 + wn + j * 16 + lm;
            u16 o[4];
#pragma unroll
            for (int r = 0; r < 4; ++r) {
                float e = __expf(acc[i][j][r] * 0.03125f);
                o[r] = f2bf(e);
                part[r] += e;
            }
#pragma unroll
            for (int r = 0; r < 4; ++r)
                C[(size_t)(rowA0 + rl0 + r) * 4096 + col] = o[r];
        }
        // reduce each row-partial across the 16 lanes of this quad
#pragma unroll
        for (int r = 0; r < 4; ++r) {
#pragma unroll
            for (int o = 8; o >= 1; o >>= 1) part[r] += __shfl_xor(part[r], o);
        }
        if (lm == 0) {
#pragma unroll
            for (int r = 0; r < 4; ++r)
                Ls[(rl0 + r) * 2 + (wave & 1)] = part[r];
        }
    }
    __syncthreads();
    const int t = threadIdx.x;
    if (t < 128)
        atomicAdd(L + z * 4096 + rowA0 + t, Ls[t * 2] + Ls[t * 2 + 1]);
}

// ------- PV: O = (P' Vt) / L -> fp32;  1/L staged through LDS --------------
// blockIdx.x = row-block (XCD swizzle for P-tile L2 reuse).
__global__ __launch_bounds__(256, 4) void gemm_pv(
    const u16* __restrict__ SP, const u16* __restrict__ Vt,
    float* __restrict__ out, const float* __restrict__ L) {
    __shared__ __align__(16) u16 As[128 * 64];
    __shared__ __align__(16) u16 Bs[128 * 64];
    const size_t z = blockIdx.z;
    const u16* A = SP + z * 16777216;
    const u16* B = Vt + z * 4194304;
    float* C = out + z * 4194304;

    const size_t rowA0 = (size_t)blockIdx.x * 128;  // row-block (swizzled)
    const size_t rowB0 = (size_t)blockIdx.y * 128;
    f32x4 acc[4][4];
    mfma_core(A, B, 4096, 4096, 4096, rowA0, rowB0, As, Bs, acc);

    // stage 1/L for this block's 128 rows in (now free) As
    float* Lsh = (float*)As;
    const int t = threadIdx.x;
    if (t < 128) Lsh[t] = 1.0f / L[z * 4096 + rowA0 + t];
    __syncthreads();

    const int lane = t & 63;
    const int wave = t >> 6;
    const int wm = (wave >> 1) * 64;
    const int wn = (wave & 1) * 64;
    const int lm = lane & 15;
    const int qd = lane >> 4;

#pragma unroll
    for (int i = 0; i < 4; ++i) {
        const int rl0 = wm + i * 16 + qd * 4;
        const int r0 = (int)rowA0 + rl0;
#pragma unroll
        for (int j = 0; j < 4; ++j) {
            const int col = (int)rowB0 + wn + j * 16 + lm;
#pragma unroll
            for (int r = 0; r < 4; ++r)
                C[(size_t)(r0 + r) * 1024 + col] = acc[i][j][r] * Lsh[rl0 + r];
        }
    }
}

// ---------------- fallback kernels (small-ws path, round-2 behavior) -------
template <int MODE>  // 2: bf16*scale, 3: fp32
__global__ __launch_bounds__(256, 3) void gemm_nt(
    const u16* __restrict__ A, const u16* __restrict__ B,
    void* __restrict__ Cv, int K, int ldA, int ldB, int ldC, float scale) {
    __shared__ __align__(16) u16 As[128 * 64];
    __shared__ __align__(16) u16 Bs[128 * 64];
    const size_t rowA0 = (size_t)blockIdx.y * 128;
    const size_t rowB0 = (size_t)blockIdx.x * 128;
    f32x4 acc[4][4];
    mfma_core(A, B, K, ldA, ldB, rowA0, rowB0, As, Bs, acc);

    const int lane = threadIdx.x & 63;
    const int wave = threadIdx.x >> 6;
    const int wm = (wave >> 1) * 64;
    const int wn = (wave & 1) * 64;
    const int lm = lane & 15;
    const int qd = lane >> 4;

#pragma unroll
    for (int i = 0; i < 4; ++i) {
        const int r0 = (int)rowA0 + wm + i * 16 + qd * 4;
#pragma unroll
        for (int j = 0; j < 4; ++j) {
            const int col = (int)rowB0 + wn + j * 16 + lm;
            if (MODE == 2) {
                u16* C = (u16*)Cv;
#pragma unroll
                for (int r = 0; r < 4; ++r)
                    C[(size_t)(r0 + r) * ldC + col] = f2bf(acc[i][j][r] * scale);
            } else {
                float* C = (float*)Cv;
#pragma unroll
                for (int r = 0; r < 4; ++r)
                    C[(size_t)(r0 + r) * ldC + col] = acc[i][j][r];
            }
        }
    }
}

__global__ __launch_bounds__(256) void softmax_inplace(u16* __restrict__ P) {
    u16* p = P + (size_t)blockIdx.x * 4096;
    const int t = threadIdx.x;
    const int lane = t & 63;
    const int wave = t >> 6;
    __shared__ float redmax[4];
    __shared__ float redsum[4];

    uint4 raw0 = *(const uint4*)(p + t * 8);
    uint4 raw1 = *(const uint4*)(p + 2048 + t * 8);
    float v[16];
    {
        const u16* h0 = (const u16*)&raw0;
        const u16* h1 = (const u16*)&raw1;
#pragma unroll
        for (int i = 0; i < 8; ++i) v[i] = bf2f(h0[i]);
#pragma unroll
        for (int i = 0; i < 8; ++i) v[8 + i] = bf2f(h1[i]);
    }
    float m = v[0];
#pragma unroll
    for (int i = 1; i < 16; ++i) m = fmaxf(m, v[i]);
#pragma unroll
    for (int o = 32; o >= 1; o >>= 1) m = fmaxf(m, __shfl_xor(m, o));
    if (lane == 0) redmax[wave] = m;
    __syncthreads();
    m = fmaxf(fmaxf(redmax[0], redmax[1]), fmaxf(redmax[2], redmax[3]));

    float s = 0.f;
#pragma unroll
    for (int i = 0; i < 16; ++i) {
        v[i] = __expf(v[i] - m);
        s += v[i];
    }
#pragma unroll
    for (int o = 32; o >= 1; o >>= 1) s += __shfl_xor(s, o);
    if (lane == 0) redsum[wave] = s;
    __syncthreads();
    s = redsum[0] + redsum[1] + redsum[2] + redsum[3];
    const float inv = 1.0f / s;

    u16 ho[16];
#pragma unroll
    for (int i = 0; i < 16; ++i) ho[i] = f2bf(v[i] * inv);
    *(uint4*)(p + t * 8) = *(const uint4*)&ho[0];
    *(uint4*)(p + 2048 + t * 8) = *(const uint4*)&ho[8];
}

// ---------------- host launcher ----------------
extern "C" void kernel_launch(void* const* d_in, const int* in_sizes, int n_in,
                              void* d_out, int out_size, void* d_ws, size_t ws_size,
                              hipStream_t stream) {
    const float* x  = (const float*)d_in[0];
    const float* Wq = (const float*)d_in[1];
    const float* bq = (const float*)d_in[2];
    const float* Wk = (const float*)d_in[3];
    const float* bk = (const float*)d_in[4];
    const float* Wv = (const float*)d_in[5];
    const float* bv = (const float*)d_in[6];
    float* out = (float*)d_out;

    const bool big = ws_size >= (size_t)234946560;  // 224 MiB + 64 KiB for L
    char* w = (char*)d_ws;
    u16 *x_bf, *wq_bf, *wk_bf, *wv_bf, *Qb, *Kb, *Vt, *SP;
    float* L = nullptr;
    if (big) {
        // SP[4] at [0,128MiB); x_bf/W alias its head (dead before SP write).
        SP    = (u16*)(w);
        x_bf  = (u16*)(w);
        wq_bf = (u16*)(w + 33554432);
        wk_bf = (u16*)(w + 35651584);
        wv_bf = (u16*)(w + 37748736);
        Qb    = (u16*)(w + 134217728);
        Kb    = (u16*)(w + 167772160);
        Vt    = (u16*)(w + 201326592);
        L     = (float*)(w + 234881024);
    } else {
        x_bf  = (u16*)(w);
        wq_bf = (u16*)(w + 33554432);
        wk_bf = (u16*)(w + 35651584);
        wv_bf = (u16*)(w + 37748736);
        Qb    = (u16*)(w + 39845888);
        Kb    = (u16*)(w + 73400320);
        Vt    = (u16*)(w + 106954752);
        SP    = (u16*)(w + 140509184);
    }

    // 1) bf16 conversions (+ L zeroing in the big path), one dispatch
    cvt_all<<<big ? 19472 : 19456, 256, 0, stream>>>(
        x, Wq, Wk, Wv, x_bf, wq_bf, wk_bf, wv_bf, L);

    // 2) fused projections: M=16384, N=1024, K=1024, z = {Q,K,V}
    proj_qkv<<<dim3(8, 128, 3), 256, 0, stream>>>(
        x_bf, wq_bf, wk_bf, wv_bf, bq, bk, bv, Qb, Kb, Vt);

    if (big) {
        // 3) P' = exp(QKt/32), L = row sums  (x = row-block for XCD reuse)
        gemm_scores<<<dim3(32, 32, 4), 256, 0, stream>>>(Qb, Kb, SP, L);
        // 4) O = (P' Vt) / L
        gemm_pv<<<dim3(32, 8, 4), 256, 0, stream>>>(SP, Vt, out, L);
    } else {
        for (int b = 0; b < 4; ++b) {
            const size_t off = (size_t)b * 4194304;
            gemm_nt<2><<<dim3(32, 32, 1), 256, 0, stream>>>(
                Qb + off, Kb + off, SP, 1024, 1024, 1024, 4096, 0.03125f);
            softmax_inplace<<<4096, 256, 0, stream>>>(SP);
            gemm_nt<3><<<dim3(8, 32, 1), 256, 0, stream>>>(
                SP, Vt + off, out + off, 4096, 4096, 4096, 1024, 1.f);
        }
    }
}